// Round 8
// baseline (71.718 us; speedup 1.0000x reference)
//
#include <hip/hip_runtime.h>
#include <math.h>

// yoloHeadv3: X (B,255,52,52) f32  ->  out (B, 3*52*52, 85) f32
// B=64, A=3 anchors, C=80 classes, G=52, ratio = 416/52 = 8.
//
// Round 8: persistent grid + cross-tile register double-buffer (T14 split).
//   - 1792 blocks (7/CU, LDS 21760 B fits 7x), 4 waves/block, each wave
//     grid-strides over wave-tiles (16 output rows each).
//   - Pipeline: prefetch next tile's 6 global loads into regs B, then
//     LDS-write/transform current regs A, ds_read + nt-store current tile.
//     Next-tile HBM latency hides under current tile's LDS+store phase.
//   - No barriers (wave-private LDS slice; per-wave DS pipe is in-order).
//   - nt stores: write-once output must not evict X from Infinity Cache.

constexpr int G   = 52;
constexpr int GG  = G * G;            // 2704
constexpr int NA  = 3;
constexpr int NC  = 85;               // channels per anchor
constexpr int RPW = 16;               // output rows per wave-tile
constexpr int WTB = GG / RPW;         // 169 wave-tiles per (b,a)
constexpr float RATIO = 8.0f;

typedef float f32x4 __attribute__((ext_vector_type(4)));

__device__ __forceinline__ float sigmoidf_(float v) {
    return 1.0f / (1.0f + expf(-v));
}

__global__ __launch_bounds__(256, 7)
void yolo_head_kernel(const float* __restrict__ X, float* __restrict__ out,
                      int total_wt, int nwaves) {
    __shared__ float lds[4 * RPW * NC];      // 4 waves * 1360 words = 21760 B

    const int w    = threadIdx.x >> 6;
    const int lane = threadIdx.x & 63;
    const int c0   = lane >> 2;              // channel offset within it-group
    const int v4   = lane & 3;               // which float4 of the 16-row chunk
    const int jl   = v4 << 2;

    float* ldsw = lds + w * (RPW * NC);
    const f32x4* lds4 = reinterpret_cast<const f32x4*>(ldsw);

    f32x4 A[6], B[6];

    auto load_tile = [&](f32x4* R, int tt) {
        const int ba  = tt / WTB;            // magic-div (169 const)
        const int rem = tt - ba * WTB;
        const f32x4* src = reinterpret_cast<const f32x4*>(X)
            + (size_t)ba * NC * (GG / 4) + (size_t)(rem * 4) + v4;
        #pragma unroll
        for (int it = 0; it < 6; ++it) {
            if (it < 5 || lane < 20) {
                R[it] = src[(size_t)(it * 16 + c0) * (GG / 4)];
            }
        }
    };

    auto process_tile = [&](f32x4* R, int tt) {
        const int ba  = tt / WTB;
        const int rem = tt - ba * WTB;
        const int ij0 = rem * RPW;
        const int a   = ba % NA;
        const float ax = (a == 0) ? 116.0f : ((a == 1) ? 156.0f : 373.0f);
        const float ay = (a == 0) ?  90.0f : ((a == 1) ? 198.0f : 326.0f);

        // ---- LDS write (transform on channels 0..4) ----
        #pragma unroll
        for (int it = 0; it < 6; ++it) {
            const int c = it * 16 + c0;
            if (it == 0) {
                if (lane < 20) {             // c in 0..4: special channels
                    #pragma unroll
                    for (int m = 0; m < 4; ++m) {
                        const int ij = ij0 + jl + m;
                        const float v = R[0][m];
                        float r;
                        if (c == 0)      r = (sigmoidf_(v) + (float)(ij % G)) * RATIO;
                        else if (c == 1) r = (sigmoidf_(v) + (float)(ij / G)) * RATIO;
                        else if (c == 2) r = fminf(expf(v), 1000.0f) * ax;
                        else if (c == 3) r = fminf(expf(v), 1000.0f) * ay;
                        else             r = sigmoidf_(v);
                        ldsw[(jl + m) * NC + c] = r;
                    }
                } else {                     // c in 5..15: passthrough classes
                    #pragma unroll
                    for (int m = 0; m < 4; ++m)
                        ldsw[(jl + m) * NC + c] = R[0][m];
                }
            } else if (it < 5 || lane < 20) {
                #pragma unroll
                for (int m = 0; m < 4; ++m)
                    ldsw[(jl + m) * NC + c] = R[it][m];
            }
        }

        // Same-wave LDS RAW is HW-ordered; stop compiler reordering only.
        asm volatile("" ::: "memory");

        // ---- store: 340 contiguous nt float4 (5440 B, 16B aligned) ----
        f32x4* dst4 = reinterpret_cast<f32x4*>(out) + (size_t)tt * (RPW * NC / 4);
        #pragma unroll
        for (int it = 0; it < 6; ++it) {
            const int idx = it * 64 + lane;
            if (it < 5 || lane < 20) {
                __builtin_nontemporal_store(lds4[idx], &dst4[idx]);
            }
        }
    };

    int t = blockIdx.x * 4 + w;              // wave-uniform tile id
    if (t >= total_wt) return;

    load_tile(A, t);
    while (true) {
        const int tn = t + nwaves;
        const bool has_next = (tn < total_wt);   // wave-uniform branch
        if (has_next) load_tile(B, tn);          // prefetch next tile
        process_tile(A, t);                      // consume current tile
        if (!has_next) break;
        t = tn;
        #pragma unroll
        for (int i = 0; i < 6; ++i) A[i] = B[i]; // rotate (static indices)
    }
}

extern "C" void kernel_launch(void* const* d_in, const int* in_sizes, int n_in,
                              void* d_out, int out_size, void* d_ws, size_t ws_size,
                              hipStream_t stream) {
    const float* X = (const float*)d_in[0];
    float* out = (float*)d_out;
    const int B = in_sizes[0] / (NA * NC * GG);       // 64
    const int total_wt = B * NA * WTB;                // 32448
    const int blocks = 1792;                          // 7 blocks/CU x 256 CUs
    const int nwaves = blocks * 4;                    // 7168 waves
    yolo_head_kernel<<<dim3((unsigned)blocks), dim3(256), 0, stream>>>(
        X, out, total_wt, nwaves);
}

// Round 9
// 64.070 us; speedup vs baseline: 1.1194x; 1.1194x over previous
//
#include <hip/hip_runtime.h>
#include <math.h>

// yoloHeadv3: X (B,255,52,52) f32  ->  out (B, 3*52*52, 85) f32
// B=64, A=3 anchors, C=80 classes, G=52, ratio = 416/52 = 8.
//
// FINAL (= round 5, best measured 64.26 us ~ 5.5 TB/s combined R+W, 87% of
// the 6.29 TB/s copy ubench). Structure:
//  - one block per (b, a, 64-ij tile): all global offsets 256B-aligned
//  - load phase : coalesced float4 reads, transform ch 0..4 (sigmoid/exp),
//                 scatter to flat LDS in EXACT output order lds[ij*85+k]
//                 (stride-85 words, 85 coprime 32 banks -> 2-way, free)
//  - store phase: linear ds_read_b128 + NONTEMPORAL global_store_dwordx4
//                 (write-once output must not evict X from 256MB L3)
// Verified no-ops/regressions: store-phase conflict fix (round 2, -71% LDS
// conflicts, 0% time), TILE=52 row-aligned (round 6, misaligns 256B, +11%),
// barrier-free wave-local (round 7, tie), persistent pipeline (round 8, +12%).

constexpr int G    = 52;
constexpr int GG   = G * G;          // 2704
constexpr int NA   = 3;
constexpr int NC   = 85;             // channels per anchor
constexpr int TILE = 64;             // ij positions per block
constexpr int NT   = (GG + TILE - 1) / TILE;  // 43 (last tile has 16)
constexpr float RATIO = 8.0f;

typedef float f32x4 __attribute__((ext_vector_type(4)));

__device__ __forceinline__ float sigmoidf_(float v) {
    return 1.0f / (1.0f + expf(-v));
}

__device__ __forceinline__ float transform_(float v, int c, int ij,
                                            float ax, float ay) {
    // c >= 5 (classes) is the common, wave-uniform fast path
    if (c >= 5) return v;
    if (c == 0) return (sigmoidf_(v) + (float)(ij % G)) * RATIO;
    if (c == 1) return (sigmoidf_(v) + (float)(ij / G)) * RATIO;
    if (c == 2) return fminf(expf(v), 1000.0f) * ax;
    if (c == 3) return fminf(expf(v), 1000.0f) * ay;
    return sigmoidf_(v);  // c == 4 (conf)
}

__global__ __launch_bounds__(256)
void yolo_head_kernel(const float* __restrict__ X, float* __restrict__ out) {
    __shared__ float lds[NC * TILE];   // 21760 B, flat: word = ij_local*85 + k

    const int bid  = blockIdx.x;
    const int tile = bid % NT;
    const int ba   = bid / NT;
    const int a    = ba % NA;
    const int b    = ba / NA;

    const int ij0 = tile * TILE;
    const bool full = (tile != NT - 1);          // last tile: n = 16

    const float ax = (a == 0) ? 116.0f : ((a == 1) ? 156.0f : 373.0f);
    const float ay = (a == 0) ?  90.0f : ((a == 1) ? 198.0f : 326.0f);

    const f32x4* src = reinterpret_cast<const f32x4*>(
        X + (((size_t)b * (NA * NC) + (size_t)a * NC) * GG + ij0));
    const int srow = GG / 4;  // 676 float4 per channel

    const int tid = threadIdx.x;

    // ---- load phase: coalesced float4 reads, transform, scatter to LDS ----
    if (full) {
        // nv = 16 float4 per channel row; total = 85*16 = 1360 items
        #pragma unroll
        for (int it = 0; it < 6; ++it) {
            const int idx = tid + it * 256;
            if (it < 5 || idx < NC * 16) {
                const int c  = idx >> 4;
                const int v4 = idx & 15;
                f32x4 val = src[(size_t)c * srow + v4];
                const int ijl = v4 << 2;
                #pragma unroll
                for (int m = 0; m < 4; ++m) {
                    lds[(ijl + m) * NC + c] =
                        transform_(val[m], c, ij0 + ijl + m, ax, ay);
                }
            }
        }
    } else {
        // nv = 4; total = 85*4 = 340 items
        #pragma unroll
        for (int it = 0; it < 2; ++it) {
            const int idx = tid + it * 256;
            if (it < 1 || idx < NC * 4) {
                const int c  = idx >> 2;
                const int v4 = idx & 3;
                f32x4 val = src[(size_t)c * srow + v4];
                const int ijl = v4 << 2;
                #pragma unroll
                for (int m = 0; m < 4; ++m) {
                    lds[(ijl + m) * NC + c] =
                        transform_(val[m], c, ij0 + ijl + m, ax, ay);
                }
            }
        }
    }

    __syncthreads();

    // ---- store phase: linear LDS -> global copy, nt dwordx4 stores ----
    f32x4* dst4 = reinterpret_cast<f32x4*>(
        out + ((size_t)b * NA * GG + (size_t)a * GG + ij0) * NC);
    const f32x4* lds4 = reinterpret_cast<const f32x4*>(lds);

    if (full) {
        // 64*85/4 = 1360 float4
        #pragma unroll
        for (int it = 0; it < 6; ++it) {
            const int idx = tid + it * 256;
            if (it < 5 || idx < (TILE * NC) / 4) {
                __builtin_nontemporal_store(lds4[idx], &dst4[idx]);
            }
        }
    } else {
        // 16*85/4 = 340 float4
        #pragma unroll
        for (int it = 0; it < 2; ++it) {
            const int idx = tid + it * 256;
            if (it < 1 || idx < (16 * NC) / 4) {
                __builtin_nontemporal_store(lds4[idx], &dst4[idx]);
            }
        }
    }
}

extern "C" void kernel_launch(void* const* d_in, const int* in_sizes, int n_in,
                              void* d_out, int out_size, void* d_ws, size_t ws_size,
                              hipStream_t stream) {
    const float* X = (const float*)d_in[0];
    float* out = (float*)d_out;
    const int B = in_sizes[0] / (NA * NC * GG);   // 64
    dim3 grid((unsigned)(B * NA * NT));
    yolo_head_kernel<<<grid, dim3(256), 0, stream>>>(X, out);
}